// Round 9
// baseline (3702.541 us; speedup 1.0000x reference)
//
#include <hip/hip_runtime.h>
#include <hip/hip_bf16.h>

#define N_NODES 100000
#define N_EDGES 1600000
// F == H == 128

// 64-node buckets
#define S2 6
#define BKN 64
#define NB2 1563              // ceil(N_NODES / 64)
#define BC2 1280              // capacity (mean 1024, +8 sigma)
#define EDGES_PER_BLK 8192
#define NBLK_EDGE ((N_EDGES + EDGES_PER_BLK - 1) / EDGES_PER_BLK)  // 196

typedef unsigned short ush8 __attribute__((ext_vector_type(8)));
typedef unsigned short ush4 __attribute__((ext_vector_type(4)));
typedef __bf16 bf8 __attribute__((ext_vector_type(8)));
typedef float f4 __attribute__((ext_vector_type(4)));

__device__ __forceinline__ float lrelu(float v) {
    return v >= 0.0f ? v : 0.01f * v;
}
__device__ __forceinline__ unsigned short f2bf(float f) {
    unsigned u = __builtin_bit_cast(unsigned, f);
    return (unsigned short)((u + 0x7FFFu + ((u >> 16) & 1u)) >> 16);
}
__device__ __forceinline__ float bfs(unsigned short u) {
    return __builtin_bit_cast(float, (unsigned)u << 16);
}
__device__ __forceinline__ float bfhi(unsigned u) {
    return __builtin_bit_cast(float, u & 0xFFFF0000u);
}
__device__ __forceinline__ float bflo(unsigned u) {
    return __builtin_bit_cast(float, u << 16);
}

// ---------------- edge binning: one pass, static bucket bases ----------------

__global__ __launch_bounds__(256) void bucket_scatter2(const int* __restrict__ src,
                                                       const int* __restrict__ dst,
                                                       int* __restrict__ bcnt,
                                                       unsigned* __restrict__ binned) {
    __shared__ int h[NB2];
    __shared__ int bbase[NB2];
    int t = threadIdx.x;
    for (int i = t; i < NB2; i += 256) h[i] = 0;
    __syncthreads();
    int base = blockIdx.x * EDGES_PER_BLK;
#pragma unroll 4
    for (int k = 0; k < EDGES_PER_BLK / 256; ++k) {
        int e = base + k * 256 + t;
        if (e < N_EDGES) atomicAdd(&h[dst[e] >> S2], 1);
    }
    __syncthreads();
    for (int i = t; i < NB2; i += 256) {
        int c = h[i];
        bbase[i] = c ? atomicAdd(&bcnt[i], c) : 0;
        h[i] = 0;  // reuse as local cursor
    }
    __syncthreads();
#pragma unroll 4
    for (int k = 0; k < EDGES_PER_BLK / 256; ++k) {
        int e = base + k * 256 + t;
        if (e < N_EDGES) {
            int d = dst[e], s = src[e];
            int b = d >> S2;
            int p = bbase[b] + atomicAdd(&h[b], 1);
            if (p < BC2)  // statically impossible overflow guard
                binned[b * BC2 + p] = ((unsigned)s << S2) | (unsigned)(d & (BKN - 1));
        }
    }
}

// per-node 1/deg (once per call)
__global__ __launch_bounds__(256) void invdeg_k(const unsigned* __restrict__ binned,
                                                const int* __restrict__ bcnt,
                                                float* __restrict__ inv) {
    __shared__ int hist[BKN];
    int b = blockIdx.x, t = threadIdx.x;
    if (t < BKN) hist[t] = 0;
    __syncthreads();
    int cnt = bcnt[b];
    cnt = (cnt < BC2) ? cnt : BC2;
    int e0 = b * BC2;
    for (int e = e0 + t; e < e0 + cnt; e += 256)
        atomicAdd(&hist[binned[e] & (BKN - 1)], 1);
    __syncthreads();
    if (t < BKN) {
        int n = b * BKN + t;
        if (n < N_NODES) inv[n] = hist[t] > 0 ? 1.0f / (float)hist[t] : 0.0f;
    }
}

// ---------------- weights ----------------
// W1T: true-k     W1T[col][k] = W1[k][col]
// W2T: permuted-k W2T[col][q] = W2[k(q)][col], k(q) = 16*(q&7) + (q>>3)
__global__ void wcast(const float* __restrict__ W1, const float* __restrict__ W2,
                      unsigned short* __restrict__ W1T, unsigned short* __restrict__ W2T) {
    int i = blockIdx.x * 256 + threadIdx.x;
    if (i >= 2 * 16384) return;
    int ii = i & 16383;
    int col = ii >> 7, q = ii & 127;
    if (i < 16384) {
        W1T[ii] = f2bf(W1[q * 128 + col]);
    } else {
        int k = 16 * (q & 7) + (q >> 3);
        W2T[ii] = f2bf(W2[k * 128 + col]);
    }
}

// ---------------- fc1: hA = bf16(lrelu(x @ W1 + b1)), permuted cols ----------------
__global__ __launch_bounds__(256) void gemm_fc1(
    const float* __restrict__ A, const unsigned short* __restrict__ WT,
    const float* __restrict__ bias, unsigned short* __restrict__ outB) {
    __shared__ unsigned short wlds[128][136];
    const int tid = threadIdx.x;
#pragma unroll
    for (int it = 0; it < 8; ++it) {
        int idx = it * 256 + tid;
        int r = idx >> 4, c = (idx & 15) << 3;
        *reinterpret_cast<ush8*>(&wlds[r][c]) =
            *reinterpret_cast<const ush8*>(&WT[r * 128 + c]);
    }

    const int lane = tid & 63, wave = tid >> 6;
    const int row0 = blockIdx.x * 64 + wave * 16;
    const int rl = lane & 15, kg = lane >> 4;
    int arow = row0 + rl;
    if (arow >= N_NODES) arow = N_NODES - 1;

    bf8 af[4];
#pragma unroll
    for (int kk = 0; kk < 4; ++kk) {
        const float* p = &A[arow * 128 + kk * 32 + kg * 8];
        float4 f0 = *reinterpret_cast<const float4*>(p);
        float4 f1 = *reinterpret_cast<const float4*>(p + 4);
        ush8 v;
        v[0] = f2bf(f0.x); v[1] = f2bf(f0.y); v[2] = f2bf(f0.z); v[3] = f2bf(f0.w);
        v[4] = f2bf(f1.x); v[5] = f2bf(f1.y); v[6] = f2bf(f1.z); v[7] = f2bf(f1.w);
        af[kk] = __builtin_bit_cast(bf8, v);
    }

    __syncthreads();

    f4 acc[8];
#pragma unroll
    for (int jt = 0; jt < 8; ++jt) acc[jt] = (f4)(0.0f);
#pragma unroll
    for (int jt = 0; jt < 8; ++jt) {
#pragma unroll
        for (int kk = 0; kk < 4; ++kk) {
            bf8 bfr = __builtin_bit_cast(
                bf8, *reinterpret_cast<const ush8*>(&wlds[jt * 16 + rl][kk * 32 + kg * 8]));
            acc[jt] = __builtin_amdgcn_mfma_f32_16x16x32_bf16(af[kk], bfr, acc[jt], 0, 0, 0);
        }
    }

    float bb[8];
#pragma unroll
    for (int j = 0; j < 8; ++j) bb[j] = bias[j * 16 + rl];

#pragma unroll
    for (int i = 0; i < 4; ++i) {
        int r = row0 + kg * 4 + i;
        if (r < N_NODES) {
            ush8 sv;
#pragma unroll
            for (int j = 0; j < 8; ++j) sv[j] = f2bf(lrelu(acc[j][i] + bb[j]));
            *reinterpret_cast<ush8*>(&outB[r * 128 + rl * 8]) = sv;
        }
    }
}

// ---------------- fused v2: edge-parallel agg into LDS + GEMM ----------------
// One block = one 64-node bucket. 512 threads (8 waves).
// Gather: waves split the bucket's contiguous edge list; per edge, the wave
// gathers h[src] (256B) and ds_add_f32's into a 2-plane f32 accumulator
// (plane 0 = even packed positions, plane 1 = odd); lane stride 4B = 2-way free.
// GEMM: A = accum * inv (f2bf), W2T read directly from global (L1-resident).
template <bool FINAL>
__global__ __launch_bounds__(512, 6) void fused2(
    const unsigned short* __restrict__ hOld, const unsigned* __restrict__ binned,
    const int* __restrict__ bcnt, const float* __restrict__ inv,
    const unsigned short* __restrict__ WT, const float* __restrict__ bias,
    float* __restrict__ outF, unsigned short* __restrict__ outB) {
    __shared__ float acc2[2][BKN][68];  // 68-f32 rows: 272B = 16B-aligned stride
    const int tid = threadIdx.x, lane = tid & 63, wave = tid >> 6;
    const int b = blockIdx.x, r0 = b * BKN;

    // zero accumulator (f4 writes)
    f4* az = reinterpret_cast<f4*>(&acc2[0][0][0]);
#pragma unroll 2
    for (int i = tid; i < 2 * BKN * 68 / 4; i += 512) az[i] = (f4)(0.0f);
    __syncthreads();

    int cnt = bcnt[b];
    cnt = (cnt < BC2) ? cnt : BC2;
    int e0 = b * BC2;
    int per = (cnt + 7) >> 3;
    int we0 = e0 + wave * per;
    int we1 = we0 + per;
    int wend = e0 + cnt;
    if (we1 > wend) we1 = wend;

    const unsigned* hb = reinterpret_cast<const unsigned*>(hOld);  // [N][64]
    int e = we0;
    for (; e + 8 <= we1; e += 8) {
        unsigned v[8];
#pragma unroll
        for (int k = 0; k < 8; ++k) v[k] = binned[e + k];
#pragma unroll
        for (int k = 0; k < 8; ++k) {
            unsigned u = hb[(v[k] >> S2) * 64 + lane];
            int dl = v[k] & (BKN - 1);
            atomicAdd(&acc2[0][dl][lane], bflo(u));
            atomicAdd(&acc2[1][dl][lane], bfhi(u));
        }
    }
    for (; e < we1; ++e) {
        unsigned v = binned[e];
        unsigned u = hb[(v >> S2) * 64 + lane];
        int dl = v & (BKN - 1);
        atomicAdd(&acc2[0][dl][lane], bflo(u));
        atomicAdd(&acc2[1][dl][lane], bfhi(u));
    }
    __syncthreads();

    // GEMM phase: wave w -> A-rows (w&3)*16..+16, jt-half (w>>2)*4
    const int rl = lane & 15, kg = lane >> 4;
    const int jh = (wave >> 2) * 4;
    const int lrow = (wave & 3) * 16 + rl;
    int grow = r0 + lrow;
    float rinv = inv[(grow < N_NODES) ? grow : (N_NODES - 1)];

    bf8 af[4];
#pragma unroll
    for (int kk = 0; kk < 4; ++kk) {
        f4 lo = *reinterpret_cast<const f4*>(&acc2[0][lrow][kk * 16 + kg * 4]);
        f4 hi = *reinterpret_cast<const f4*>(&acc2[1][lrow][kk * 16 + kg * 4]);
        ush8 t;
#pragma unroll
        for (int m = 0; m < 4; ++m) {
            t[2 * m]     = f2bf(lo[m] * rinv);
            t[2 * m + 1] = f2bf(hi[m] * rinv);
        }
        af[kk] = __builtin_bit_cast(bf8, t);
    }

    f4 accm[4];
#pragma unroll
    for (int j = 0; j < 4; ++j) accm[j] = (f4)(0.0f);
#pragma unroll
    for (int j = 0; j < 4; ++j) {
        int jt = jh + j;
#pragma unroll
        for (int kk = 0; kk < 4; ++kk) {
            bf8 bw = __builtin_bit_cast(
                bf8, *reinterpret_cast<const ush8*>(
                         &WT[(jt * 16 + rl) * 128 + kk * 32 + kg * 8]));
            accm[j] = __builtin_amdgcn_mfma_f32_16x16x32_bf16(af[kk], bw, accm[j], 0, 0, 0);
        }
    }

    float bb[4];
#pragma unroll
    for (int j = 0; j < 4; ++j) bb[j] = bias[(jh + j) * 16 + rl];

#pragma unroll
    for (int i = 0; i < 4; ++i) {
        int r = r0 + (wave & 3) * 16 + kg * 4 + i;
        if (r < N_NODES) {
            ush4 rv = *reinterpret_cast<const ush4*>(&hOld[r * 128 + rl * 8 + jh]);
            float v[4];
#pragma unroll
            for (int j = 0; j < 4; ++j)
                v[j] = lrelu(accm[j][i] + bb[j] + bfs(rv[j]));
            if (FINAL) {
#pragma unroll
                for (int j = 0; j < 4; ++j)
                    outF[r * 128 + (jh + j) * 16 + rl] = v[j];
            } else {
                ush4 sv;
#pragma unroll
                for (int j = 0; j < 4; ++j) sv[j] = f2bf(v[j]);
                *reinterpret_cast<ush4*>(&outB[r * 128 + rl * 8 + jh]) = sv;
            }
        }
    }
}

// ---------------- launch ----------------

extern "C" void kernel_launch(void* const* d_in, const int* in_sizes, int n_in,
                              void* d_out, int out_size, void* d_ws, size_t ws_size,
                              hipStream_t stream) {
    const float* x  = (const float*)d_in[0];
    const float* W1 = (const float*)d_in[1];
    const float* b1 = (const float*)d_in[2];
    const float* W2 = (const float*)d_in[3];
    const float* b2 = (const float*)d_in[4];
    const int* esrc = (const int*)d_in[5];
    const int* edst = (const int*)d_in[6];
    float* out = (float*)d_out;

    char* ws = (char*)d_ws;
    size_t o = 0;
    auto alloc = [&](size_t b) {
        void* p = ws + o;
        o += (b + 511) & ~(size_t)511;
        return p;
    };
    int* bcnt = (int*)alloc(NB2 * 4);
    float* inv = (float*)alloc((size_t)N_NODES * 4);
    unsigned* binned = (unsigned*)alloc((size_t)NB2 * BC2 * 4);  // 8.0 MB, live all call
    unsigned short* W1T = (unsigned short*)alloc(128 * 128 * 2);
    unsigned short* W2T = (unsigned short*)alloc(128 * 128 * 2);
    unsigned short* hA = (unsigned short*)alloc((size_t)N_NODES * 128 * 2);
    unsigned short* hC = (unsigned short*)alloc((size_t)N_NODES * 128 * 2);

    hipMemsetAsync(bcnt, 0, NB2 * 4, stream);
    bucket_scatter2<<<NBLK_EDGE, 256, 0, stream>>>(esrc, edst, bcnt, binned);
    invdeg_k<<<NB2, 256, 0, stream>>>(binned, bcnt, inv);

    wcast<<<(2 * 16384 + 255) / 256, 256, 0, stream>>>(W1, W2, W1T, W2T);

    const int GB = (N_NODES + 63) / 64;  // 1563
    gemm_fc1<<<GB, 256, 0, stream>>>(x, W1T, b1, hA);

    // double-buffered synchronous iterations
    fused2<false><<<NB2, 512, 0, stream>>>(hA, binned, bcnt, inv, W2T, b2,
                                           nullptr, hC);
    fused2<false><<<NB2, 512, 0, stream>>>(hC, binned, bcnt, inv, W2T, b2,
                                           nullptr, hA);
    fused2<true><<<NB2, 512, 0, stream>>>(hA, binned, bcnt, inv, W2T, b2,
                                          out, nullptr);
}

// Round 10
// 665.587 us; speedup vs baseline: 5.5628x; 5.5628x over previous
//
#include <hip/hip_runtime.h>
#include <hip/hip_bf16.h>

#define N_NODES 100000
#define N_EDGES 1600000
// F == H == 128

// 64-node buckets
#define S2 6
#define BKN 64
#define NB2 1563              // ceil(N_NODES / 64)
#define BC2 1280              // capacity (mean 1024, +8 sigma)
#define EDGES_PER_BLK 8192
#define NBLK_EDGE ((N_EDGES + EDGES_PER_BLK - 1) / EDGES_PER_BLK)  // 196

#define FXS 65536.0f          // fixed-point scale 2^16
#define FXI 1.52587890625e-05f  // 2^-16

typedef unsigned short ush8 __attribute__((ext_vector_type(8)));
typedef unsigned short ush4 __attribute__((ext_vector_type(4)));
typedef __bf16 bf8 __attribute__((ext_vector_type(8)));
typedef float f4 __attribute__((ext_vector_type(4)));
typedef int i4 __attribute__((ext_vector_type(4)));

__device__ __forceinline__ float lrelu(float v) {
    return v >= 0.0f ? v : 0.01f * v;
}
__device__ __forceinline__ unsigned short f2bf(float f) {
    unsigned u = __builtin_bit_cast(unsigned, f);
    return (unsigned short)((u + 0x7FFFu + ((u >> 16) & 1u)) >> 16);
}
__device__ __forceinline__ float bfs(unsigned short u) {
    return __builtin_bit_cast(float, (unsigned)u << 16);
}
__device__ __forceinline__ float bfhi(unsigned u) {
    return __builtin_bit_cast(float, u & 0xFFFF0000u);
}
__device__ __forceinline__ float bflo(unsigned u) {
    return __builtin_bit_cast(float, u << 16);
}

// ---------------- edge binning: one pass, static bucket bases ----------------

__global__ __launch_bounds__(256) void bucket_scatter2(const int* __restrict__ src,
                                                       const int* __restrict__ dst,
                                                       int* __restrict__ bcnt,
                                                       unsigned* __restrict__ binned) {
    __shared__ int h[NB2];
    __shared__ int bbase[NB2];
    int t = threadIdx.x;
    for (int i = t; i < NB2; i += 256) h[i] = 0;
    __syncthreads();
    int base = blockIdx.x * EDGES_PER_BLK;
#pragma unroll 4
    for (int k = 0; k < EDGES_PER_BLK / 256; ++k) {
        int e = base + k * 256 + t;
        if (e < N_EDGES) atomicAdd(&h[dst[e] >> S2], 1);
    }
    __syncthreads();
    for (int i = t; i < NB2; i += 256) {
        int c = h[i];
        bbase[i] = c ? atomicAdd(&bcnt[i], c) : 0;
        h[i] = 0;  // reuse as local cursor
    }
    __syncthreads();
#pragma unroll 4
    for (int k = 0; k < EDGES_PER_BLK / 256; ++k) {
        int e = base + k * 256 + t;
        if (e < N_EDGES) {
            int d = dst[e], s = src[e];
            int b = d >> S2;
            int p = bbase[b] + atomicAdd(&h[b], 1);
            if (p < BC2)  // statically impossible overflow guard
                binned[b * BC2 + p] = ((unsigned)s << S2) | (unsigned)(d & (BKN - 1));
        }
    }
}

// per-node 1/deg (once per call)
__global__ __launch_bounds__(256) void invdeg_k(const unsigned* __restrict__ binned,
                                                const int* __restrict__ bcnt,
                                                float* __restrict__ inv) {
    __shared__ int hist[BKN];
    int b = blockIdx.x, t = threadIdx.x;
    if (t < BKN) hist[t] = 0;
    __syncthreads();
    int cnt = bcnt[b];
    cnt = (cnt < BC2) ? cnt : BC2;
    int e0 = b * BC2;
    for (int e = e0 + t; e < e0 + cnt; e += 256)
        atomicAdd(&hist[binned[e] & (BKN - 1)], 1);
    __syncthreads();
    if (t < BKN) {
        int n = b * BKN + t;
        if (n < N_NODES) inv[n] = hist[t] > 0 ? 1.0f / (float)hist[t] : 0.0f;
    }
}

// ---------------- weights ----------------
// W1T: true-k     W1T[col][k] = W1[k][col]
// W2T: permuted-k W2T[col][q] = W2[k(q)][col], k(q) = 16*(q&7) + (q>>3)
__global__ void wcast(const float* __restrict__ W1, const float* __restrict__ W2,
                      unsigned short* __restrict__ W1T, unsigned short* __restrict__ W2T) {
    int i = blockIdx.x * 256 + threadIdx.x;
    if (i >= 2 * 16384) return;
    int ii = i & 16383;
    int col = ii >> 7, q = ii & 127;
    if (i < 16384) {
        W1T[ii] = f2bf(W1[q * 128 + col]);
    } else {
        int k = 16 * (q & 7) + (q >> 3);
        W2T[ii] = f2bf(W2[k * 128 + col]);
    }
}

// ---------------- fc1: hA = bf16(lrelu(x @ W1 + b1)), permuted cols ----------------
__global__ __launch_bounds__(256) void gemm_fc1(
    const float* __restrict__ A, const unsigned short* __restrict__ WT,
    const float* __restrict__ bias, unsigned short* __restrict__ outB) {
    __shared__ unsigned short wlds[128][136];
    const int tid = threadIdx.x;
#pragma unroll
    for (int it = 0; it < 8; ++it) {
        int idx = it * 256 + tid;
        int r = idx >> 4, c = (idx & 15) << 3;
        *reinterpret_cast<ush8*>(&wlds[r][c]) =
            *reinterpret_cast<const ush8*>(&WT[r * 128 + c]);
    }

    const int lane = tid & 63, wave = tid >> 6;
    const int row0 = blockIdx.x * 64 + wave * 16;
    const int rl = lane & 15, kg = lane >> 4;
    int arow = row0 + rl;
    if (arow >= N_NODES) arow = N_NODES - 1;

    bf8 af[4];
#pragma unroll
    for (int kk = 0; kk < 4; ++kk) {
        const float* p = &A[arow * 128 + kk * 32 + kg * 8];
        float4 f0 = *reinterpret_cast<const float4*>(p);
        float4 f1 = *reinterpret_cast<const float4*>(p + 4);
        ush8 v;
        v[0] = f2bf(f0.x); v[1] = f2bf(f0.y); v[2] = f2bf(f0.z); v[3] = f2bf(f0.w);
        v[4] = f2bf(f1.x); v[5] = f2bf(f1.y); v[6] = f2bf(f1.z); v[7] = f2bf(f1.w);
        af[kk] = __builtin_bit_cast(bf8, v);
    }

    __syncthreads();

    f4 acc[8];
#pragma unroll
    for (int jt = 0; jt < 8; ++jt) acc[jt] = (f4)(0.0f);
#pragma unroll
    for (int jt = 0; jt < 8; ++jt) {
#pragma unroll
        for (int kk = 0; kk < 4; ++kk) {
            bf8 bfr = __builtin_bit_cast(
                bf8, *reinterpret_cast<const ush8*>(&wlds[jt * 16 + rl][kk * 32 + kg * 8]));
            acc[jt] = __builtin_amdgcn_mfma_f32_16x16x32_bf16(af[kk], bfr, acc[jt], 0, 0, 0);
        }
    }

    float bb[8];
#pragma unroll
    for (int j = 0; j < 8; ++j) bb[j] = bias[j * 16 + rl];

#pragma unroll
    for (int i = 0; i < 4; ++i) {
        int r = row0 + kg * 4 + i;
        if (r < N_NODES) {
            ush8 sv;
#pragma unroll
            for (int j = 0; j < 8; ++j) sv[j] = f2bf(lrelu(acc[j][i] + bb[j]));
            *reinterpret_cast<ush8*>(&outB[r * 128 + rl * 8]) = sv;
        }
    }
}

// ---------------- fused v2: edge-parallel agg into LDS + GEMM ----------------
// One block = one 64-node bucket. 512 threads (8 waves).
// Gather: waves split the bucket's contiguous edge list; per edge, the wave
// gathers h[src] (256B) and accumulates into a 2-plane FIXED-POINT (2^16) int
// accumulator via native ds_add_u32 (HIP float atomicAdd on LDS compiles to a
// CAS loop -> 18x slowdown, round-9 lesson). Lane stride 4B = 2-way free.
// GEMM: A = accum * 2^-16 * inv (f2bf), W2T read from global (L2-resident).
template <bool FINAL>
__global__ __launch_bounds__(512, 6) void fused2(
    const unsigned short* __restrict__ hOld, const unsigned* __restrict__ binned,
    const int* __restrict__ bcnt, const float* __restrict__ inv,
    const unsigned short* __restrict__ WT, const float* __restrict__ bias,
    float* __restrict__ outF, unsigned short* __restrict__ outB) {
    __shared__ int acc2[2][BKN][68];  // 68-int rows: 272B = 16B-aligned stride
    const int tid = threadIdx.x, lane = tid & 63, wave = tid >> 6;
    const int b = blockIdx.x, r0 = b * BKN;

    // zero accumulator (i4 writes)
    i4* az = reinterpret_cast<i4*>(&acc2[0][0][0]);
#pragma unroll 2
    for (int i = tid; i < 2 * BKN * 68 / 4; i += 512) az[i] = (i4)(0);
    __syncthreads();

    int cnt = bcnt[b];
    cnt = (cnt < BC2) ? cnt : BC2;
    int e0 = b * BC2;
    int per = (cnt + 7) >> 3;
    int we0 = e0 + wave * per;
    int we1 = we0 + per;
    int wend = e0 + cnt;
    if (we1 > wend) we1 = wend;

    const unsigned* hb = reinterpret_cast<const unsigned*>(hOld);  // [N][64]
    int e = we0;
    for (; e + 8 <= we1; e += 8) {
        unsigned v[8];
#pragma unroll
        for (int k = 0; k < 8; ++k) v[k] = binned[e + k];
#pragma unroll
        for (int k = 0; k < 8; ++k) {
            unsigned u = hb[(v[k] >> S2) * 64 + lane];
            int dl = v[k] & (BKN - 1);
            atomicAdd(&acc2[0][dl][lane], (int)rintf(bflo(u) * FXS));
            atomicAdd(&acc2[1][dl][lane], (int)rintf(bfhi(u) * FXS));
        }
    }
    for (; e < we1; ++e) {
        unsigned v = binned[e];
        unsigned u = hb[(v >> S2) * 64 + lane];
        int dl = v & (BKN - 1);
        atomicAdd(&acc2[0][dl][lane], (int)rintf(bflo(u) * FXS));
        atomicAdd(&acc2[1][dl][lane], (int)rintf(bfhi(u) * FXS));
    }
    __syncthreads();

    // GEMM phase: wave w -> A-rows (w&3)*16..+16, jt-half (w>>2)*4
    const int rl = lane & 15, kg = lane >> 4;
    const int jh = (wave >> 2) * 4;
    const int lrow = (wave & 3) * 16 + rl;
    int grow = r0 + lrow;
    float rinv = inv[(grow < N_NODES) ? grow : (N_NODES - 1)] * FXI;

    bf8 af[4];
#pragma unroll
    for (int kk = 0; kk < 4; ++kk) {
        i4 lo = *reinterpret_cast<const i4*>(&acc2[0][lrow][kk * 16 + kg * 4]);
        i4 hi = *reinterpret_cast<const i4*>(&acc2[1][lrow][kk * 16 + kg * 4]);
        ush8 t;
#pragma unroll
        for (int m = 0; m < 4; ++m) {
            t[2 * m]     = f2bf((float)lo[m] * rinv);
            t[2 * m + 1] = f2bf((float)hi[m] * rinv);
        }
        af[kk] = __builtin_bit_cast(bf8, t);
    }

    f4 accm[4];
#pragma unroll
    for (int j = 0; j < 4; ++j) accm[j] = (f4)(0.0f);
#pragma unroll
    for (int j = 0; j < 4; ++j) {
        int jt = jh + j;
#pragma unroll
        for (int kk = 0; kk < 4; ++kk) {
            bf8 bw = __builtin_bit_cast(
                bf8, *reinterpret_cast<const ush8*>(
                         &WT[(jt * 16 + rl) * 128 + kk * 32 + kg * 8]));
            accm[j] = __builtin_amdgcn_mfma_f32_16x16x32_bf16(af[kk], bw, accm[j], 0, 0, 0);
        }
    }

    float bb[4];
#pragma unroll
    for (int j = 0; j < 4; ++j) bb[j] = bias[(jh + j) * 16 + rl];

#pragma unroll
    for (int i = 0; i < 4; ++i) {
        int r = r0 + (wave & 3) * 16 + kg * 4 + i;
        if (r < N_NODES) {
            ush4 rv = *reinterpret_cast<const ush4*>(&hOld[r * 128 + rl * 8 + jh]);
            float v[4];
#pragma unroll
            for (int j = 0; j < 4; ++j)
                v[j] = lrelu(accm[j][i] + bb[j] + bfs(rv[j]));
            if (FINAL) {
#pragma unroll
                for (int j = 0; j < 4; ++j)
                    outF[r * 128 + (jh + j) * 16 + rl] = v[j];
            } else {
                ush4 sv;
#pragma unroll
                for (int j = 0; j < 4; ++j) sv[j] = f2bf(v[j]);
                *reinterpret_cast<ush4*>(&outB[r * 128 + rl * 8 + jh]) = sv;
            }
        }
    }
}

// ---------------- launch ----------------

extern "C" void kernel_launch(void* const* d_in, const int* in_sizes, int n_in,
                              void* d_out, int out_size, void* d_ws, size_t ws_size,
                              hipStream_t stream) {
    const float* x  = (const float*)d_in[0];
    const float* W1 = (const float*)d_in[1];
    const float* b1 = (const float*)d_in[2];
    const float* W2 = (const float*)d_in[3];
    const float* b2 = (const float*)d_in[4];
    const int* esrc = (const int*)d_in[5];
    const int* edst = (const int*)d_in[6];
    float* out = (float*)d_out;

    char* ws = (char*)d_ws;
    size_t o = 0;
    auto alloc = [&](size_t b) {
        void* p = ws + o;
        o += (b + 511) & ~(size_t)511;
        return p;
    };
    int* bcnt = (int*)alloc(NB2 * 4);
    float* inv = (float*)alloc((size_t)N_NODES * 4);
    unsigned* binned = (unsigned*)alloc((size_t)NB2 * BC2 * 4);  // 8.0 MB, live all call
    unsigned short* W1T = (unsigned short*)alloc(128 * 128 * 2);
    unsigned short* W2T = (unsigned short*)alloc(128 * 128 * 2);
    unsigned short* hA = (unsigned short*)alloc((size_t)N_NODES * 128 * 2);
    unsigned short* hC = (unsigned short*)alloc((size_t)N_NODES * 128 * 2);

    hipMemsetAsync(bcnt, 0, NB2 * 4, stream);
    bucket_scatter2<<<NBLK_EDGE, 256, 0, stream>>>(esrc, edst, bcnt, binned);
    invdeg_k<<<NB2, 256, 0, stream>>>(binned, bcnt, inv);

    wcast<<<(2 * 16384 + 255) / 256, 256, 0, stream>>>(W1, W2, W1T, W2T);

    const int GB = (N_NODES + 63) / 64;  // 1563
    gemm_fc1<<<GB, 256, 0, stream>>>(x, W1T, b1, hA);

    // double-buffered synchronous iterations
    fused2<false><<<NB2, 512, 0, stream>>>(hA, binned, bcnt, inv, W2T, b2,
                                           nullptr, hC);
    fused2<false><<<NB2, 512, 0, stream>>>(hC, binned, bcnt, inv, W2T, b2,
                                           nullptr, hA);
    fused2<true><<<NB2, 512, 0, stream>>>(hA, binned, bcnt, inv, W2T, b2,
                                          out, nullptr);
}